// Round 4
// baseline (78.596 us; speedup 1.0000x reference)
//
#include <hip/hip_runtime.h>
#include <hip/hip_cooperative_groups.h>

namespace cg = cooperative_groups;

#define RW 8
#define LARGE_V 1e10f
#define MAXI 10            // max iterations the LDS stack supports
#define NV 1024            // n (compile-time; problem is fixed-shape)
#define NC 512             // m
#define SCALE 1048576.0f   // 2^20 fixed-point scale for deterministic LDS accumulation
#define INV_SCALE (1.0f / 1048576.0f)

// One cooperative kernel: phase 0 extracts H's column structure + casts labels
// (parallelized over all B*8 waves), grid.sync, then per-block BP decode.
__global__ __launch_bounds__(512) void fused_bp_kernel(
    const float* __restrict__ soft_in,
    const int* __restrict__ labels,
    const int* __restrict__ H,
    const float* __restrict__ normalizer,
    float* __restrict__ out,
    int* __restrict__ cols,
    int B, int niter)
{
    __shared__ float stack[MAXI + 1][NV];   // all output slices stay in LDS
    __shared__ int   iacc[NV];              // fixed-point message accumulator

    const int tid  = threadIdx.x;
    const int lane = tid & 63;
    const int wav  = tid >> 6;              // 0..7
    const int gw   = blockIdx.x * 8 + wav;  // global wave id, 0..B*8-1

    // ---------- setup: extract RW cols of H row gw (one wave per row) ----------
    if (gw < NC) {
        const int4* rp = (const int4*)(H + (size_t)gw * NV + lane * 16);
        int v[16];
        #pragma unroll
        for (int q = 0; q < 4; ++q) {
            int4 x = rp[q];
            v[q * 4 + 0] = x.x; v[q * 4 + 1] = x.y;
            v[q * 4 + 2] = x.z; v[q * 4 + 3] = x.w;
        }
        int cnt = 0;
        #pragma unroll
        for (int e = 0; e < 16; ++e) cnt += (v[e] != 0);
        int pre = cnt;                      // wave exclusive prefix-sum
        #pragma unroll
        for (int d = 1; d < 64; d <<= 1) {
            int o = __shfl_up(pre, d);
            if (lane >= d) pre += o;
        }
        pre -= cnt;
        int k = 0;
        #pragma unroll
        for (int e = 0; e < 16; ++e) {
            if (v[e] != 0) {
                if (pre + k < RW) cols[gw * RW + pre + k] = lane * 16 + e;
                ++k;
            }
        }
    }
    // ---------- setup: labels int32 -> f32 (one wave per 128-elem chunk) ----------
    {
        const int lab_total = B * NV;
        float* out_labels = out + (size_t)(niter + 1) * lab_total;
        int base = gw * 128 + lane * 2;
        if (base + 1 < lab_total) {
            int2 x = *(const int2*)(labels + base);
            float2 f; f.x = (float)x.x; f.y = (float)x.y;
            *(float2*)(out_labels + base) = f;
        }
    }

    __threadfence();            // release cols stores (cross-XCD)
    cg::this_grid().sync();
    __threadfence();            // acquire before reading other XCDs' cols

    // ---------- BP: one block per batch element, thread tid owns check tid ----------
    const int b = blockIdx.x;
    const float norm = log1pf(expf(normalizer[0]));   // softplus

    int c[RW];
    {
        const int4* cp = (const int4*)(cols + tid * RW);  // NC == blockDim
        int4 a0 = cp[0], a1 = cp[1];
        c[0] = a0.x; c[1] = a0.y; c[2] = a0.z; c[3] = a0.w;
        c[4] = a1.x; c[5] = a1.y; c[6] = a1.z; c[7] = a1.w;
    }
    {
        const int j0 = tid * 2;
        float2 s = *(const float2*)(soft_in + (size_t)b * NV + j0);
        *(float2*)&stack[0][j0] = s;
        int2 z; z.x = 0; z.y = 0;
        *(int2*)&iacc[j0] = z;
    }
    __syncthreads();

    int ni = (niter > MAXI) ? MAXI : niter;

    for (int t = 0; t < ni; ++t) {
        const float* cur = stack[t];

        // --- check-node phase ---
        float a[RW], p[RW];
        unsigned int sb[RW];
        unsigned int sx = 0;      // XOR of sign bits = sign of product
        bool anyz = false;        // any exactly-zero message -> all msgs 0
        #pragma unroll
        for (int k = 0; k < RW; ++k) {
            float vv = cur[c[k]];
            unsigned int bits = __float_as_uint(vv);
            sb[k] = bits & 0x80000000u;
            sx ^= sb[k];
            float av = fabsf(vv);
            a[k] = av;
            anyz = anyz || (av == 0.0f);
            p[k] = (av == 0.0f) ? LARGE_V : av;   // reference: proc
        }
        // top-2 min tree over p[0..7]
        float l0 = fminf(p[0], p[1]), h0 = fmaxf(p[0], p[1]);
        float l1 = fminf(p[2], p[3]), h1 = fmaxf(p[2], p[3]);
        float l2 = fminf(p[4], p[5]), h2 = fmaxf(p[4], p[5]);
        float l3 = fminf(p[6], p[7]), h3 = fmaxf(p[6], p[7]);
        float m1a = fminf(l0, l1);
        float m2a = fminf(fmaxf(l0, l1), fminf(h0, h1));
        float m1b = fminf(l2, l3);
        float m2b = fminf(fmaxf(l2, l3), fminf(h2, h3));
        float mn1 = fminf(m1a, m1b);
        float mn2 = fminf(fmaxf(m1a, m1b), fminf(m2a, m2b));

        float nm1 = norm * mn1, nm2 = norm * mn2;
        #pragma unroll
        for (int k = 0; k < RW; ++k) {
            float mag = (a[k] == mn1) ? nm2 : nm1;   // top-2 min-sum select
            unsigned int mb = __float_as_uint(mag) ^ (sx ^ sb[k]);
            float msg = anyz ? 0.0f : __uint_as_float(mb);
            atomicAdd(&iacc[c[k]], __float2int_rn(msg * SCALE));  // ds_add native
        }
        __syncthreads();

        // --- variable-node phase: 2 vars per thread, re-zero iacc ---
        {
            const int j0 = tid * 2;
            float2 sp = *(const float2*)&stack[t][j0];
            int2 ia = *(const int2*)&iacc[j0];
            float2 nv2;
            nv2.x = sp.x + (float)ia.x * INV_SCALE;
            nv2.y = sp.y + (float)ia.y * INV_SCALE;
            *(float2*)&stack[t + 1][j0] = nv2;
            int2 z; z.x = 0; z.y = 0;
            *(int2*)&iacc[j0] = z;
        }
        __syncthreads();
    }

    // ---------- coalesced writeout of all (ni+1) slices ----------
    const int total4 = (ni + 1) * (NV / 4);
    for (int idx = tid; idx < total4; idx += 512) {
        int slice = idx >> 8;          // NV/4 == 256
        int pos   = idx & 255;
        float4 val = *(const float4*)&stack[slice][pos * 4];
        *(float4*)(out + ((size_t)slice * B + b) * NV + (size_t)pos * 4) = val;
    }
}

extern "C" void kernel_launch(void* const* d_in, const int* in_sizes, int n_in,
                              void* d_out, int out_size, void* d_ws, size_t ws_size,
                              hipStream_t stream) {
    const float* soft_in    = (const float*)d_in[0];
    const int*   labels     = (const int*)d_in[1];
    const int*   H          = (const int*)d_in[2];
    const float* normalizer = (const float*)d_in[3];
    float*       out        = (float*)d_out;

    int B     = in_sizes[0] / NV;              // 128
    int niter = out_size / (B * NV) - 2;       // 10
    int* cols = (int*)d_ws;                    // NC*RW ints = 16 KB scratch

    void* args[8] = { (void*)&soft_in, (void*)&labels, (void*)&H, (void*)&normalizer,
                      (void*)&out, (void*)&cols, (void*)&B, (void*)&niter };
    hipLaunchCooperativeKernel((const void*)fused_bp_kernel, dim3(B), dim3(512),
                               args, 0, stream);
}

// Round 5
// 21.617 us; speedup vs baseline: 3.6359x; 3.6359x over previous
//
#include <hip/hip_runtime.h>

#define RW 8
#define LARGE_V 1e10f
#define MAXI 10            // max iterations the LDS stack supports
#define NV 1024            // n (fixed problem shape)
#define NC 512             // m
#define SCALE 1048576.0f   // 2^20 fixed-point scale for deterministic LDS accumulation
#define INV_SCALE (1.0f / 1048576.0f)

// One wave per H row: coalesced int4 loads + wave prefix-sum -> RW ascending
// column indices per check row.
__global__ __launch_bounds__(64) void extract_cols_kernel(const int* __restrict__ H,
                                                          int* __restrict__ cols) {
    const int i    = blockIdx.x;   // row
    const int lane = threadIdx.x;  // 0..63

    const int4* rp = (const int4*)(H + (size_t)i * NV + lane * 16);
    int v[16];
    #pragma unroll
    for (int q = 0; q < 4; ++q) {
        int4 x = rp[q];
        v[q * 4 + 0] = x.x; v[q * 4 + 1] = x.y;
        v[q * 4 + 2] = x.z; v[q * 4 + 3] = x.w;
    }
    int cnt = 0;
    #pragma unroll
    for (int e = 0; e < 16; ++e) cnt += (v[e] != 0);
    int pre = cnt;                 // wave exclusive prefix-sum
    #pragma unroll
    for (int d = 1; d < 64; d <<= 1) {
        int o = __shfl_up(pre, d);
        if (lane >= d) pre += o;
    }
    pre -= cnt;
    int k = 0;
    #pragma unroll
    for (int e = 0; e < 16; ++e) {
        if (v[e] != 0) {
            if (pre + k < RW) cols[i * RW + pre + k] = lane * 16 + e;
            ++k;
        }
    }
}

// One block (1024 threads, 16 waves) per batch element. Two threads per check:
// thread tid owns edges (tid&1)*4..+4 of check tid>>1; partner-lane combine via
// shfl_xor(,1) (DPP quad-perm). Output stack lives in LDS; int fixed-point LDS
// atomics (native ds_add, deterministic).
__global__ __launch_bounds__(1024) void bp_kernel(const float* __restrict__ soft_in,
                                                  const int* __restrict__ labels,
                                                  const int* __restrict__ cols,
                                                  const float* __restrict__ normalizer,
                                                  float* __restrict__ out,
                                                  int B, int niter) {
    __shared__ float stack[MAXI + 1][NV];
    __shared__ int   iacc[NV];

    const int b   = blockIdx.x;
    const int tid = threadIdx.x;

    // init: soft slice 0, zero acc, labels cast (store drains at first barrier)
    {
        stack[0][tid] = soft_in[(size_t)b * NV + tid];
        iacc[tid] = 0;
        float* out_labels = out + (size_t)(niter + 1) * B * NV;
        out_labels[(size_t)b * NV + tid] = (float)labels[(size_t)b * NV + tid];
    }

    // my 4 edges: check tid>>1, half tid&1 (coalesced int4 per thread)
    int c[4];
    {
        int4 a4 = *(const int4*)(cols + (tid >> 1) * RW + (tid & 1) * 4);
        c[0] = a4.x & (NV - 1); c[1] = a4.y & (NV - 1);
        c[2] = a4.z & (NV - 1); c[3] = a4.w & (NV - 1);
    }
    const float norm = log1pf(expf(normalizer[0]));  // softplus
    __syncthreads();

    int ni = (niter > MAXI) ? MAXI : niter;

    for (int t = 0; t < ni; ++t) {
        const float* cur = stack[t];

        // --- check-node phase: 4 edges per thread ---
        float a[4], p[4];
        unsigned int sb[4];
        unsigned int sxa = 0;
        bool anyz = false;
        #pragma unroll
        for (int k = 0; k < 4; ++k) {
            float vv = cur[c[k]];
            unsigned int bits = __float_as_uint(vv);
            sb[k] = bits & 0x80000000u;
            sxa ^= sb[k];
            float av = fabsf(vv);
            a[k] = av;
            anyz = anyz || (av == 0.0f);
            p[k] = (av == 0.0f) ? LARGE_V : av;     // reference: proc
        }
        // pack: bit31 = sign-xor of my half, bit0 = anyz of my half
        sxa = (sxa & 0x80000000u) | (anyz ? 1u : 0u);
        unsigned int oth = (unsigned int)__shfl_xor((int)sxa, 1);
        const unsigned int prodsign = (sxa ^ oth) & 0x80000000u;  // full-row sign product
        const bool zz = ((sxa | oth) & 1u) != 0u;                 // any zero in row

        // top-2 min of my 4, then combine with partner
        float l0 = fminf(p[0], p[1]), h0 = fmaxf(p[0], p[1]);
        float l1 = fminf(p[2], p[3]), h1 = fmaxf(p[2], p[3]);
        float m1 = fminf(l0, l1);
        float m2 = fminf(fmaxf(l0, l1), fminf(h0, h1));
        float m1o = __shfl_xor(m1, 1);
        float m2o = __shfl_xor(m2, 1);
        const float mn1 = fminf(m1, m1o);
        const float mn2 = fminf(fmaxf(m1, m1o), fminf(m2, m2o));

        const float nm1 = norm * mn1, nm2 = norm * mn2;
        #pragma unroll
        for (int k = 0; k < 4; ++k) {
            float mag = (a[k] == mn1) ? nm2 : nm1;  // top-2 min-sum select
            unsigned int mb = __float_as_uint(mag) ^ (prodsign ^ sb[k]);
            float msg = zz ? 0.0f : __uint_as_float(mb);
            atomicAdd(&iacc[c[k]], __float2int_rn(msg * SCALE));  // native ds_add
        }
        __syncthreads();

        // --- variable-node phase: 1 var per thread ---
        {
            float sp = stack[t][tid];
            int   ia = iacc[tid];
            stack[t + 1][tid] = sp + (float)ia * INV_SCALE;
            iacc[tid] = 0;
        }
        __syncthreads();
    }

    // --- coalesced writeout of all (ni+1) slices ---
    const int total4 = (ni + 1) * (NV / 4);
    for (int idx = tid; idx < total4; idx += 1024) {
        int slice = idx >> 8;   // NV/4 == 256
        int pos   = idx & 255;
        float4 val = *(const float4*)&stack[slice][pos * 4];
        *(float4*)(out + ((size_t)slice * B + b) * NV + (size_t)pos * 4) = val;
    }
}

extern "C" void kernel_launch(void* const* d_in, const int* in_sizes, int n_in,
                              void* d_out, int out_size, void* d_ws, size_t ws_size,
                              hipStream_t stream) {
    const float* soft_in    = (const float*)d_in[0];
    const int*   labels     = (const int*)d_in[1];
    const int*   H          = (const int*)d_in[2];
    const float* normalizer = (const float*)d_in[3];

    const int B     = in_sizes[0] / NV;          // 128
    const int niter = out_size / (B * NV) - 2;   // 10

    int* cols = (int*)d_ws;                      // NC*RW ints = 16 KB scratch

    extract_cols_kernel<<<NC, 64, 0, stream>>>(H, cols);
    bp_kernel<<<B, 1024, 0, stream>>>(soft_in, labels, cols, normalizer,
                                      (float*)d_out, B, niter);
}

// Round 6
// 20.546 us; speedup vs baseline: 3.8254x; 1.0521x over previous
//
#include <hip/hip_runtime.h>

#define RW 8
#define LARGE_V 1e10f
#define NV 1024            // n (fixed problem shape)
#define NC 512             // m
#define SCALE 1048576.0f   // 2^20 fixed-point scale for deterministic LDS accumulation
#define INV_SCALE (1.0f / 1048576.0f)

// LDS-only barrier: wait local ops, raw s_barrier (no vmcnt drain, so global
// stores issued in the loop stay in flight until kernel end).
#define LDS_BARRIER() do { \
    asm volatile("s_waitcnt lgkmcnt(0)" ::: "memory"); \
    __builtin_amdgcn_s_barrier(); \
} while (0)

// Fused setup grid: blocks [0,NC) extract the RW ascending column indices of
// one H row each (coalesced int4 + wave prefix-sum); blocks [NC, NC+labBlocks)
// cast labels int32 -> f32 into the tail of out.
__global__ __launch_bounds__(64) void setup_kernel(const int* __restrict__ H,
                                                   int* __restrict__ cols,
                                                   const int* __restrict__ labels,
                                                   float* __restrict__ out_labels,
                                                   int lab_total) {
    const int blk  = blockIdx.x;
    const int lane = threadIdx.x;  // 0..63

    if (blk < NC) {
        const int4* rp = (const int4*)(H + (size_t)blk * NV + lane * 16);
        int v[16];
        #pragma unroll
        for (int q = 0; q < 4; ++q) {
            int4 x = rp[q];
            v[q * 4 + 0] = x.x; v[q * 4 + 1] = x.y;
            v[q * 4 + 2] = x.z; v[q * 4 + 3] = x.w;
        }
        int cnt = 0;
        #pragma unroll
        for (int e = 0; e < 16; ++e) cnt += (v[e] != 0);
        int pre = cnt;                 // wave exclusive prefix-sum
        #pragma unroll
        for (int d = 1; d < 64; d <<= 1) {
            int o = __shfl_up(pre, d);
            if (lane >= d) pre += o;
        }
        pre -= cnt;
        int k = 0;
        #pragma unroll
        for (int e = 0; e < 16; ++e) {
            if (v[e] != 0) {
                if (pre + k < RW) cols[blk * RW + pre + k] = lane * 16 + e;
                ++k;
            }
        }
    } else {
        const int base = (blk - NC) * 1024 + lane * 16;
        if (base + 15 < lab_total) {
            #pragma unroll
            for (int q = 0; q < 4; ++q) {
                int4 x = *(const int4*)(labels + base + q * 4);
                float4 f;
                f.x = (float)x.x; f.y = (float)x.y;
                f.z = (float)x.z; f.w = (float)x.w;
                *(float4*)(out_labels + base + q * 4) = f;
            }
        }
    }
}

// One block (1024 threads, 16 waves) per batch element. Two threads per check
// (4 edges each), partner combine via shfl_xor(,1). Single soft[] buffer in
// LDS; thread tid owns variable tid (running value in register sv). Each
// iteration's slice streams to global fire-and-forget (raw barriers don't
// drain vmcnt).
__global__ __launch_bounds__(1024) void bp_kernel(const float* __restrict__ soft_in,
                                                  const int* __restrict__ cols,
                                                  const float* __restrict__ normalizer,
                                                  float* __restrict__ out,
                                                  int B, int niter) {
    __shared__ float soft[NV];
    __shared__ int   iacc[NV];

    const int b   = blockIdx.x;
    const int tid = threadIdx.x;
    const size_t BN = (size_t)B * NV;

    // my 4 edges: check tid>>1, half tid&1 (coalesced int4 per thread)
    int c[4];
    {
        int4 a4 = *(const int4*)(cols + (tid >> 1) * RW + (tid & 1) * 4);
        c[0] = a4.x & (NV - 1); c[1] = a4.y & (NV - 1);
        c[2] = a4.z & (NV - 1); c[3] = a4.w & (NV - 1);
    }
    const float norm = log1pf(expf(normalizer[0]));  // softplus(normalizer)

    // init: running soft value in register; slice 0 streamed to global
    float sv = soft_in[(size_t)b * NV + tid];
    soft[tid] = sv;
    iacc[tid] = 0;
    out[(size_t)b * NV + tid] = sv;
    LDS_BARRIER();

    for (int t = 0; t < niter; ++t) {
        // --- check-node phase: 4 edges per thread ---
        float a[4], p[4];
        unsigned int sb[4];
        unsigned int sxa = 0;
        bool anyz = false;
        #pragma unroll
        for (int k = 0; k < 4; ++k) {
            float vv = soft[c[k]];
            unsigned int bits = __float_as_uint(vv);
            sb[k] = bits & 0x80000000u;
            sxa ^= sb[k];
            float av = fabsf(vv);
            a[k] = av;
            anyz = anyz || (av == 0.0f);
            p[k] = (av == 0.0f) ? LARGE_V : av;     // reference: proc
        }
        // pack: bit31 = sign-xor of my half, bit0 = anyz of my half
        sxa = (sxa & 0x80000000u) | (anyz ? 1u : 0u);
        unsigned int oth = (unsigned int)__shfl_xor((int)sxa, 1);
        const unsigned int prodsign = (sxa ^ oth) & 0x80000000u;  // row sign product
        const bool zz = ((sxa | oth) & 1u) != 0u;                 // any zero in row

        // top-2 min of my 4, then combine with partner
        float l0 = fminf(p[0], p[1]), h0 = fmaxf(p[0], p[1]);
        float l1 = fminf(p[2], p[3]), h1 = fmaxf(p[2], p[3]);
        float m1 = fminf(l0, l1);
        float m2 = fminf(fmaxf(l0, l1), fminf(h0, h1));
        float m1o = __shfl_xor(m1, 1);
        float m2o = __shfl_xor(m2, 1);
        const float mn1 = fminf(m1, m1o);
        const float mn2 = fminf(fmaxf(m1, m1o), fminf(m2, m2o));

        // pre-scaled integer messages (rounding sign-symmetric == per-edge rn)
        int im1 = zz ? 0 : __float2int_rn(norm * mn1 * SCALE);
        int im2 = zz ? 0 : __float2int_rn(norm * mn2 * SCALE);
        int nm1i = -im1, nm2i = -im2;
        #pragma unroll
        for (int k = 0; k < 4; ++k) {
            bool sel = (a[k] == mn1);               // top-2 min-sum select
            bool neg = ((prodsign ^ sb[k]) != 0u);  // extrinsic sign
            int mag = sel ? im2 : im1;
            int nmg = sel ? nm2i : nm1i;
            atomicAdd(&iacc[c[k]], neg ? nmg : mag);  // native ds_add
        }
        LDS_BARRIER();

        // --- variable-node phase: 1 var per thread, stream slice to global ---
        {
            int ia = atomicExch(&iacc[tid], 0);     // ds_wrxchg: read+zero in one op
            sv += (float)ia * INV_SCALE;
            soft[tid] = sv;
            out[(size_t)(t + 1) * BN + (size_t)b * NV + tid] = sv;  // fire-and-forget
        }
        LDS_BARRIER();
    }
}

extern "C" void kernel_launch(void* const* d_in, const int* in_sizes, int n_in,
                              void* d_out, int out_size, void* d_ws, size_t ws_size,
                              hipStream_t stream) {
    const float* soft_in    = (const float*)d_in[0];
    const int*   labels     = (const int*)d_in[1];
    const int*   H          = (const int*)d_in[2];
    const float* normalizer = (const float*)d_in[3];

    const int B     = in_sizes[0] / NV;          // 128
    const int niter = out_size / (B * NV) - 2;   // 10

    int* cols = (int*)d_ws;                      // NC*RW ints = 16 KB scratch

    const int lab_total  = B * NV;
    const int lab_blocks = (lab_total + 1023) / 1024;
    float* out_labels = (float*)d_out + (size_t)(niter + 1) * lab_total;

    setup_kernel<<<NC + lab_blocks, 64, 0, stream>>>(H, cols, labels,
                                                     out_labels, lab_total);
    bp_kernel<<<B, 1024, 0, stream>>>(soft_in, cols, normalizer,
                                      (float*)d_out, B, niter);
}

// Round 7
// 20.481 us; speedup vs baseline: 3.8375x; 1.0032x over previous
//
#include <hip/hip_runtime.h>

#define RW 8
#define LARGE_V 1e10f
#define NV 1024            // n (fixed problem shape)
#define NC 512             // m
#define SCALE 524288.0f    // 2^19 fixed-point scale (cumulative sum: ample headroom)
#define INV_SCALE (1.0f / 524288.0f)

// LDS-only barrier: wait local ops, raw s_barrier (no vmcnt drain, so global
// stores issued in the loop stay in flight until kernel end).
#define LDS_BARRIER() do { \
    asm volatile("s_waitcnt lgkmcnt(0)" ::: "memory"); \
    __builtin_amdgcn_s_barrier(); \
} while (0)

// Fused setup grid: blocks [0,NC) extract the RW ascending column indices of
// one H row each (coalesced int4 + wave prefix-sum); blocks [NC, NC+labBlocks)
// cast labels int32 -> f32 into the tail of out.
__global__ __launch_bounds__(64) void setup_kernel(const int* __restrict__ H,
                                                   int* __restrict__ cols,
                                                   const int* __restrict__ labels,
                                                   float* __restrict__ out_labels,
                                                   int lab_total) {
    const int blk  = blockIdx.x;
    const int lane = threadIdx.x;  // 0..63

    if (blk < NC) {
        const int4* rp = (const int4*)(H + (size_t)blk * NV + lane * 16);
        int v[16];
        #pragma unroll
        for (int q = 0; q < 4; ++q) {
            int4 x = rp[q];
            v[q * 4 + 0] = x.x; v[q * 4 + 1] = x.y;
            v[q * 4 + 2] = x.z; v[q * 4 + 3] = x.w;
        }
        int cnt = 0;
        #pragma unroll
        for (int e = 0; e < 16; ++e) cnt += (v[e] != 0);
        int pre = cnt;                 // wave exclusive prefix-sum
        #pragma unroll
        for (int d = 1; d < 64; d <<= 1) {
            int o = __shfl_up(pre, d);
            if (lane >= d) pre += o;
        }
        pre -= cnt;
        int k = 0;
        #pragma unroll
        for (int e = 0; e < 16; ++e) {
            if (v[e] != 0) {
                if (pre + k < RW) cols[blk * RW + pre + k] = lane * 16 + e;
                ++k;
            }
        }
    } else {
        const int base = (blk - NC) * 1024 + lane * 16;
        if (base + 15 < lab_total) {
            #pragma unroll
            for (int q = 0; q < 4; ++q) {
                int4 x = *(const int4*)(labels + base + q * 4);
                float4 f;
                f.x = (float)x.x; f.y = (float)x.y;
                f.z = (float)x.z; f.w = (float)x.w;
                *(float4*)(out_labels + base + q * 4) = f;
            }
        }
    }
}

// One block (1024 threads) per batch element; two threads per check (4 edges
// each), partner combine via shfl_xor(,1). All soft values live in REGISTERS;
// iacc is a cumulative (never-zeroed) fixed-point message sum, so:
//   soft_t[j] = soft0[j] + iacc_t[j] * INV_SCALE   (exact int accumulation).
// Check phase: pure-register VALU + 4 ds_add. Update phase: 5 ds_read + FMA +
// fire-and-forget global slice store + precompute of next check inputs.
__global__ __launch_bounds__(1024) void bp_kernel(const float* __restrict__ soft_in,
                                                  const int* __restrict__ cols,
                                                  const float* __restrict__ normalizer,
                                                  float* __restrict__ out,
                                                  int B, int niter) {
    __shared__ float s0[NV];
    __shared__ int   iacc[NV];

    const int b   = blockIdx.x;
    const int tid = threadIdx.x;
    const size_t BN = (size_t)B * NV;

    // my 4 edges: check tid>>1, half tid&1 (coalesced int4 per thread)
    int c[4];
    {
        int4 a4 = *(const int4*)(cols + (tid >> 1) * RW + (tid & 1) * 4);
        c[0] = a4.x & (NV - 1); c[1] = a4.y & (NV - 1);
        c[2] = a4.z & (NV - 1); c[3] = a4.w & (NV - 1);
    }
    const float norm = log1pf(expf(normalizer[0]));  // softplus(normalizer)

    // init: stage soft row (coalesced), zero iacc, stream slice 0
    const float msoft = soft_in[(size_t)b * NV + tid];
    s0[tid]   = msoft;
    iacc[tid] = 0;
    out[(size_t)b * NV + tid] = msoft;
    LDS_BARRIER();

    float s0k[4];
    #pragma unroll
    for (int k = 0; k < 4; ++k) s0k[k] = s0[c[k]];

    // precompute check inputs for iteration 0 from register soft values
    float a[4]; unsigned int sb[4]; float m1, m2; unsigned int sxa;
    {
        float p[4]; unsigned int sx = 0; bool anyz = false;
        #pragma unroll
        for (int k = 0; k < 4; ++k) {
            float v = s0k[k];
            unsigned int bits = __float_as_uint(v);
            sb[k] = bits & 0x80000000u; sx ^= sb[k];
            float av = fabsf(v); a[k] = av;
            anyz = anyz || (av == 0.0f);
            p[k] = (av == 0.0f) ? LARGE_V : av;       // reference: proc
        }
        float l0 = fminf(p[0], p[1]), h0 = fmaxf(p[0], p[1]);
        float l1 = fminf(p[2], p[3]), h1 = fmaxf(p[2], p[3]);
        m1 = fminf(l0, l1);
        m2 = fminf(fmaxf(l0, l1), fminf(h0, h1));
        sxa = (sx & 0x80000000u) | (anyz ? 1u : 0u);  // bit31 sign-xor, bit0 anyz
    }

    for (int t = 0; t < niter; ++t) {
        // --- check phase: partner combine + 4 atomics (pure registers in) ---
        unsigned int oth = (unsigned int)__shfl_xor((int)sxa, 1);
        const unsigned int prodsign = (sxa ^ oth) & 0x80000000u;  // row sign product
        const bool zz = ((sxa | oth) & 1u) != 0u;                 // any zero in row
        float m1o = __shfl_xor(m1, 1);
        float m2o = __shfl_xor(m2, 1);
        const float mn1 = fminf(m1, m1o);
        const float mn2 = fminf(fmaxf(m1, m1o), fminf(m2, m2o));
        const int im1 = zz ? 0 : __float2int_rn(norm * mn1 * SCALE);
        const int im2 = zz ? 0 : __float2int_rn(norm * mn2 * SCALE);
        #pragma unroll
        for (int k = 0; k < 4; ++k) {
            int mag = (a[k] == mn1) ? im2 : im1;      // top-2 min-sum select
            int v   = ((prodsign ^ sb[k]) != 0u) ? -mag : mag;
            atomicAdd(&iacc[c[k]], v);                // native ds_add (cumulative)
        }
        LDS_BARRIER();

        // --- update phase: read back cumulative sums, recompute soft in regs ---
        int cum[4];
        #pragma unroll
        for (int k = 0; k < 4; ++k) cum[k] = iacc[c[k]];
        const int cumo = iacc[tid];
        const float svo = msoft + (float)cumo * INV_SCALE;
        out[(size_t)(t + 1) * BN + (size_t)b * NV + tid] = svo;  // fire-and-forget

        // precompute next iteration's check inputs (hidden under read latency)
        {
            float p[4]; unsigned int sx = 0; bool anyz = false;
            #pragma unroll
            for (int k = 0; k < 4; ++k) {
                float v = s0k[k] + (float)cum[k] * INV_SCALE;
                unsigned int bits = __float_as_uint(v);
                sb[k] = bits & 0x80000000u; sx ^= sb[k];
                float av = fabsf(v); a[k] = av;
                anyz = anyz || (av == 0.0f);
                p[k] = (av == 0.0f) ? LARGE_V : av;
            }
            float l0 = fminf(p[0], p[1]), h0 = fmaxf(p[0], p[1]);
            float l1 = fminf(p[2], p[3]), h1 = fmaxf(p[2], p[3]);
            m1 = fminf(l0, l1);
            m2 = fminf(fmaxf(l0, l1), fminf(h0, h1));
            sxa = (sx & 0x80000000u) | (anyz ? 1u : 0u);
        }
        LDS_BARRIER();
    }
}

extern "C" void kernel_launch(void* const* d_in, const int* in_sizes, int n_in,
                              void* d_out, int out_size, void* d_ws, size_t ws_size,
                              hipStream_t stream) {
    const float* soft_in    = (const float*)d_in[0];
    const int*   labels     = (const int*)d_in[1];
    const int*   H          = (const int*)d_in[2];
    const float* normalizer = (const float*)d_in[3];

    const int B     = in_sizes[0] / NV;          // 128
    const int niter = out_size / (B * NV) - 2;   // 10

    int* cols = (int*)d_ws;                      // NC*RW ints = 16 KB scratch

    const int lab_total  = B * NV;
    const int lab_blocks = (lab_total + 1023) / 1024;
    float* out_labels = (float*)d_out + (size_t)(niter + 1) * lab_total;

    setup_kernel<<<NC + lab_blocks, 64, 0, stream>>>(H, cols, labels,
                                                     out_labels, lab_total);
    bp_kernel<<<B, 1024, 0, stream>>>(soft_in, cols, normalizer,
                                      (float*)d_out, B, niter);
}